// Round 2
// baseline (232.755 us; speedup 1.0000x reference)
//
#include <hip/hip_runtime.h>

// Problem constants (from reference)
#define VOCAB 50257
#define SEQ   2048
#define EMB   512
#define BATCH 8
#define NTOK  (BATCH * SEQ)   // 16384

// Workspace-free fused kernel.
//
// Grid: (ceil(VOCAB/64) = 786, 2).  Block: 256 threads (4 waves).
// Each block owns a 64-wide vocab tile and a 256-wide emb half:
//   1. Stage slab[64][256] of W_emb (EMB,VOCAB) into LDS.
//      Per wave-inst: 64 lanes read 256 B contiguous along vocab  -> coalesced.
//      LDS row stride 257 floats -> bank (tx + e) % 32, 2-way only -> free.
//   2. Scan tokens (64 KB, L2-resident) in 8 chunks of 2048; collect matches
//      (t in [v0, v0+64)) into an LDS list. Chunk size == list capacity, so
//      overflow is impossible for ANY input.
//   3. Per match: all 256 threads write one contiguous 1 KB row segment,
//      out[p][eoff..eoff+256) = slab[vl][:] + Wpos[p & 2047][eoff..), fused
//      single f32 add (bit-identical to reference), nontemporal store.
//
// Traffic: W_emb read exactly once (100.6 MB), out written once (33.5 MB),
// tokens re-scanned from L2 (~100 MB L2-side, ~0 HBM). No workspace touched.

#define CHUNK 2048            // token-scan chunk == match-list capacity
#define NCHUNK (NTOK / CHUNK) // 8

__global__ __launch_bounds__(256)
void slab_scatter_k(const int* __restrict__ tokens,
                    const float* __restrict__ W,     // (EMB, VOCAB)
                    const float* __restrict__ Wpos,  // (SEQ, EMB)
                    float* __restrict__ out) {       // (NTOK, EMB)
    __shared__ float slab[64][257];                  // 65.8 KB
    __shared__ int   m_p[CHUNK];                     // 8 KB
    __shared__ unsigned char m_vl[CHUNK];            // 2 KB
    __shared__ int   nmatch;

    const int v0   = blockIdx.x * 64;
    const int eoff = blockIdx.y * 256;
    const int tid  = threadIdx.x;
    const int tx   = tid & 63;                       // lane
    const int ty   = tid >> 6;                       // wave

    if (tid == 0) nmatch = 0;

    // --- 1. slab load (issued first; completion guaranteed by the first
    //        __syncthreads below, which drains vm/lgkm for all threads) ---
    const int v = v0 + tx;
    if (v < VOCAB) {
        const float* rp = W + (size_t)(eoff + ty) * VOCAB + v;
#pragma unroll
        for (int j = 0; j < 64; ++j)
            slab[tx][4 * j + ty] = rp[(size_t)(4 * j) * VOCAB];
    }

    // --- 2+3. chunked scan + scatter ---
    for (int c = 0; c < NCHUNK; ++c) {
        const int base = c * CHUNK;
#pragma unroll
        for (int k = 0; k < CHUNK / 256; ++k) {
            const int i = base + k * 256 + tid;      // coalesced, L2-hit
            const unsigned d = (unsigned)(tokens[i] - v0);
            if (d < 64u) {
                const int m = atomicAdd(&nmatch, 1); // ~2.6 matches/chunk avg
                m_p[m]  = i;
                m_vl[m] = (unsigned char)d;
            }
        }
        __syncthreads();                             // matches + slab ready
        const int nm = nmatch;
        for (int m = 0; m < nm; ++m) {
            const int p  = m_p[m];
            const int vl = m_vl[m];
            const int s  = p & (SEQ - 1);
            const float r = slab[vl][tid]
                          + Wpos[(size_t)s * EMB + eoff + tid];
            __builtin_nontemporal_store(
                r, &out[(size_t)p * EMB + eoff + tid]);
        }
        __syncthreads();                             // list consumed
        if (tid == 0) nmatch = 0;
        __syncthreads();                             // reset visible
    }
}

extern "C" void kernel_launch(void* const* d_in, const int* in_sizes, int n_in,
                              void* d_out, int out_size, void* d_ws, size_t ws_size,
                              hipStream_t stream) {
    const int*   tokens = (const int*)d_in[0];
    const float* W_emb  = (const float*)d_in[1];   // (EMB, VOCAB)
    const float* W_pos  = (const float*)d_in[2];   // (SEQ, EMB)
    float*       out    = (float*)d_out;           // (BATCH*SEQ, EMB)

    (void)d_ws; (void)ws_size;                     // workspace deliberately unused

    slab_scatter_k<<<dim3((VOCAB + 63) / 64, EMB / 256), 256, 0, stream>>>(
        tokens, W_emb, W_pos, out);
}

// Round 3
// 219.921 us; speedup vs baseline: 1.0584x; 1.0584x over previous
//
#include <hip/hip_runtime.h>

// Problem constants (from reference)
#define VOCAB 50257
#define SEQ   2048
#define EMB   512
#define BATCH 8
#define NTOK  (BATCH * SEQ)   // 16384

typedef float floatx2 __attribute__((ext_vector_type(2)));

// Workspace-free fused embedding-gather, wave-parallel schedule.
//
// Grid: (ceil(VOCAB/64) = 786, EMB/128 = 4).  Block: 256 threads (4 waves).
// Each block owns a 64-wide vocab tile and a 128-wide emb quarter.
//
//   1. Stage slab[64][128] of W_emb into LDS, PERMUTED within the e-axis:
//      local e' is stored at column (e'&1)*64 + (e'>>1).  Staging writes are
//      stride-129 across lanes (2-way bank alias, free); match-loop reads are
//      lane-contiguous (conflict-free).  Global reads: 64 lanes x 4 B = 256 B
//      contiguous per wave-inst, fully coalesced.
//   2. ONE barrier.  Then each wave independently scans its quarter of the
//      16384 tokens (coalesced, L2-resident) and drains matches immediately
//      via ballot/ctz — no LDS list, no atomics, no more barriers.
//   3. Per match: wave writes one contiguous 512 B row segment,
//      out[p][eoff+2l..] = slab-col + Wpos[p&2047][...], fused single f32 add
//      (bit-identical to reference), nontemporal dwordx2 store.
//
// LDS = 64*129*4 = 33 KB -> 4 blocks/CU, 16 waves/CU (2x round-2 occupancy).
// Traffic: W_emb read exactly once (100.6 MB), out written once (33.5 MB),
// tokens re-scanned from L2 (~206 MB L2-side ~= 6 us). No workspace touched.

__global__ __launch_bounds__(256)
void slab_scatter_k(const int* __restrict__ tokens,
                    const float* __restrict__ W,     // (EMB, VOCAB)
                    const floatx2* __restrict__ Wpos2, // (SEQ, EMB/2)
                    floatx2* __restrict__ out2) {    // (NTOK, EMB/2)
    __shared__ float slab[64][129];                  // 33 KB

    const int v0   = blockIdx.x * 64;
    const int eoff = blockIdx.y * 128;               // e-quarter base
    const int tid  = threadIdx.x;
    const int lane = tid & 63;
    const int wv   = tid >> 6;                       // wave 0..3
    const int v    = v0 + lane;

    // --- 1. staged, permuted slab load ---
    if (v < VOCAB) {
        const float* rp = W + (size_t)(eoff + wv) * VOCAB + v;
        const int cbase = (wv & 1) * 64 + (wv >> 1);
#pragma unroll
        for (int j = 0; j < 32; ++j) {
            // e' = 4j + wv  ->  column (e'&1)*64 + (e'>>1) = cbase + 2j
            slab[lane][cbase + 2 * j] = rp[(size_t)(4 * j) * VOCAB];
        }
    }
    __syncthreads();                                 // the only barrier

    // --- 2+3. wave-independent scan + scatter ---
    const int wbase = wv * (NTOK / 4);
    const int ecol2 = (eoff >> 1) + lane;            // floatx2 column index
#pragma unroll 4
    for (int k = 0; k < (NTOK / 4) / 64; ++k) {      // 64 iterations
        const int i = wbase + k * 64 + lane;
        const unsigned d = (unsigned)(tokens[i] - v0);
        unsigned long long mask = __ballot(d < 64u);
        while (mask) {
            const int b = (int)__builtin_ctzll(mask);
            mask &= mask - 1;
            const int p  = wbase + k * 64 + b;       // output row (uniform)
            const int vl = __shfl((int)d, b);        // local vocab idx
            const int s  = p & (SEQ - 1);
            const float* wrow = slab[vl];
            const floatx2 wp = Wpos2[(size_t)s * (EMB / 2) + ecol2];
            floatx2 r;
            r.x = wrow[lane];                        // e' = 2*lane
            r.y = wrow[64 + lane];                   // e' = 2*lane + 1
            __builtin_nontemporal_store(
                r + wp, &out2[(size_t)p * (EMB / 2) + ecol2]);
        }
    }
}

extern "C" void kernel_launch(void* const* d_in, const int* in_sizes, int n_in,
                              void* d_out, int out_size, void* d_ws, size_t ws_size,
                              hipStream_t stream) {
    const int*   tokens = (const int*)d_in[0];
    const float* W_emb  = (const float*)d_in[1];   // (EMB, VOCAB)
    const float* W_pos  = (const float*)d_in[2];   // (SEQ, EMB)
    float*       out    = (float*)d_out;           // (BATCH*SEQ, EMB)

    (void)d_ws; (void)ws_size;                     // workspace deliberately unused

    slab_scatter_k<<<dim3((VOCAB + 63) / 64, EMB / 128), 256, 0, stream>>>(
        tokens, W_emb, (const floatx2*)W_pos, (floatx2*)out);
}

// Round 4
// 177.079 us; speedup vs baseline: 1.3144x; 1.2419x over previous
//
#include <hip/hip_runtime.h>

// Problem constants (from reference)
#define VOCAB 50257
#define SEQ   2048
#define EMB   512
#define BATCH 8
#define NTOK  (BATCH * SEQ)   // 16384

typedef float floatx2 __attribute__((ext_vector_type(2)));

// ---------------------------------------------------------------------------
// Scan-free fused embedding gather.
//
// Index build (2 tiny kernels, ~5 us):
//   head[v]  : last output-row using vocab v, -1 if unused   (VOCAB ints)
//   next[i]  : previous row with the same token as row i     (NTOK ints)
//   built with one atomicExch per token -- no histogram, no prefix scan.
//
// slab_scatter_k (the fat kernel), grid (786, 4), 256 thr:
//   1. Wave 0 ballot-compacts the used columns of its 64-wide vocab tile
//      from head[] (~17.8 used cols, ~21 output rows per block).
//   2. All 4 waves stage slab[64][128] of W_emb into LDS, e-permuted
//      (col = (e&1)*64 + e>>1) -> staging writes 2-way aliased (free),
//      drain reads lane-contiguous (conflict-free; round-3 verified 0).
//      Global reads: 256 B contiguous per wave-inst, fully coalesced.
//   3. One barrier. Waves round-robin the used columns; per column the
//      slab read is hoisted (once), then the ~1.2-long chain is walked:
//      out[p][eoff..eoff+128) = col + Wpos[p&2047][...], fused single f32
//      add (bit-identical to reference), nontemporal 512 B dwordx2 rows.
//
// No per-block token rescan (round 3 paid 206 MB of L2 + a 64-iter
// serial ballot loop for it -- that was 75% of its 100 us).
// LDS 33.5 KB -> 4 blocks/CU, 16 waves/CU.
// Traffic: W_emb read once (100.6 MB), out written once (33.5 MB).
// ---------------------------------------------------------------------------

#define HEAD_OFF 0
#define NEXT_OFF 50432                // head padded to 50432
#define WS_INTS  (NEXT_OFF + NTOK)    // ~267 KB

__global__ __launch_bounds__(256)
void init_head_k(int* __restrict__ head) {
    const int i = blockIdx.x * 256 + threadIdx.x;
    if (i < VOCAB) head[i] = -1;
}

__global__ __launch_bounds__(256)
void links_k(const int* __restrict__ tokens, int* __restrict__ head,
             int* __restrict__ next) {
    const int i = blockIdx.x * 256 + threadIdx.x;   // grid = NTOK/256
    next[i] = atomicExch(&head[tokens[i]], i);
}

__global__ __launch_bounds__(256)
void slab_scatter_k(const int* __restrict__ head,
                    const int* __restrict__ next,
                    const float* __restrict__ W,       // (EMB, VOCAB)
                    const floatx2* __restrict__ Wpos2, // (SEQ, EMB/2)
                    floatx2* __restrict__ out2) {      // (NTOK, EMB/2)
    __shared__ float slab[64][129];                    // 33 KB
    __shared__ int   u_vl[64];
    __shared__ int   u_hd[64];
    __shared__ int   nused_s;

    const int v0   = blockIdx.x * 64;
    const int eoff = blockIdx.y * 128;
    const int tid  = threadIdx.x;
    const int lane = tid & 63;
    const int wv   = tid >> 6;
    const int v    = v0 + lane;

    // --- 1. compact used columns (wave 0 only) ---
    if (tid < 64) {
        const int h = (v < VOCAB) ? head[v] : -1;
        const unsigned long long m = __ballot(h >= 0);
        const int pos = __popcll(m & ((1ull << lane) - 1ull));
        if (h >= 0) { u_vl[pos] = lane; u_hd[pos] = h; }
        if (lane == 0) nused_s = (int)__popcll(m);
    }

    // --- 2. staged, permuted slab load (all waves) ---
    if (v < VOCAB) {
        const float* rp = W + (size_t)(eoff + wv) * VOCAB + v;
        const int cbase = (wv & 1) * 64 + (wv >> 1);
#pragma unroll
        for (int j = 0; j < 32; ++j) {
            // e' = 4j + wv -> column (e'&1)*64 + (e'>>1) = cbase + 2j
            slab[lane][cbase + 2 * j] = rp[(size_t)(4 * j) * VOCAB];
        }
    }
    __syncthreads();                                   // slab + list ready

    // --- 3. chain-walk scatter, waves independent ---
    const int nused = nused_s;
    const int ecol2 = (eoff >> 1) + lane;              // floatx2 column
    for (int u = wv; u < nused; u += 4) {
        const int vl = u_vl[u];
        int p = u_hd[u];
        floatx2 col;
        col.x = slab[vl][lane];                        // e' = 2*lane
        col.y = slab[vl][64 + lane];                   // e' = 2*lane + 1
        while (p >= 0) {
            const int s = p & (SEQ - 1);
            const floatx2 r = col + Wpos2[(size_t)s * (EMB / 2) + ecol2];
            __builtin_nontemporal_store(
                r, &out2[(size_t)p * (EMB / 2) + ecol2]);
            p = next[p];                               // ~1.2 hops avg, L2
        }
    }
}

// Fallback: direct strided gather (correct anywhere, slow).
typedef float floatx4 __attribute__((ext_vector_type(4)));
__global__ __launch_bounds__(256)
void gather_direct_k(const int* __restrict__ tokens,
                     const float* __restrict__ W_emb,
                     const floatx4* __restrict__ Wpos,
                     floatx4* __restrict__ out) {
    const int idx = blockIdx.x * blockDim.x + threadIdx.x;
    const int e4  = idx & (EMB / 4 - 1);
    const int ts  = idx >> 7;
    const int s   = ts & (SEQ - 1);
    const int t   = tokens[ts];
    const size_t base = (size_t)(4 * e4) * VOCAB + (size_t)t;
    floatx4 r;
    r.x = W_emb[base];
    r.y = W_emb[base + (size_t)VOCAB];
    r.z = W_emb[base + (size_t)(2 * VOCAB)];
    r.w = W_emb[base + (size_t)(3 * VOCAB)];
    __builtin_nontemporal_store(r + Wpos[(size_t)s * (EMB / 4) + e4], &out[idx]);
}

extern "C" void kernel_launch(void* const* d_in, const int* in_sizes, int n_in,
                              void* d_out, int out_size, void* d_ws, size_t ws_size,
                              hipStream_t stream) {
    const int*   tokens = (const int*)d_in[0];
    const float* W_emb  = (const float*)d_in[1];   // (EMB, VOCAB)
    const float* W_pos  = (const float*)d_in[2];   // (SEQ, EMB)
    float*       out    = (float*)d_out;           // (BATCH*SEQ, EMB)

    const size_t need = (size_t)WS_INTS * sizeof(int);   // ~267 KB
    if (ws_size >= need) {
        int* head = (int*)d_ws + HEAD_OFF;
        int* next = (int*)d_ws + NEXT_OFF;

        init_head_k<<<(VOCAB + 255) / 256, 256, 0, stream>>>(head);
        links_k<<<NTOK / 256, 256, 0, stream>>>(tokens, head, next);
        slab_scatter_k<<<dim3((VOCAB + 63) / 64, EMB / 128), 256, 0, stream>>>(
            head, next, W_emb, (const floatx2*)W_pos, (floatx2*)out);
    } else {
        const int gblocks = BATCH * SEQ * (EMB / 4) / 256;
        gather_direct_k<<<gblocks, 256, 0, stream>>>(tokens, W_emb,
                                                     (const floatx4*)W_pos,
                                                     (floatx4*)out);
    }
}